// Round 26
// baseline (509.621 us; speedup 1.0000x reference)
//
#include <hip/hip_runtime.h>
#include <math.h>

#define EPS 1e-3f
#define H 256
#define QDIM 6
#define NTRI 10

typedef _Float16 half8 __attribute__((ext_vector_type(8)));
typedef float floatx4 __attribute__((ext_vector_type(4)));

#define WSZ (H * H)
#define MFMA(A, B, C) __builtin_amdgcn_mfma_f32_16x16x32_f16((A), (B), (C), 0, 0, 0)

__device__ __forceinline__ float softplusf(float x) {
    if (x > 20.f) return x;
    return log1pf(expf(x));
}

// ---- prep: fragment-packed fp16 B matrices; W2t fp32; W2A fp16 ----
// packed index for logical B[r][c]: jt=r>>4, fr=r&15, kc=c>>5, fg=(c>>3)&3, ii=c&7
//   Bp[((jt*8+kc)*64 + fg*16+fr)*8 + ii]
__global__ __launch_bounds__(256) void prep_kernel(
    const float* __restrict__ mW1, const float* __restrict__ vW1,
    const float* __restrict__ mW2, void* __restrict__ ws)
{
    char* wsb = (char*)ws;
    _Float16* W1t_p = (_Float16*)(wsb + 0 * WSZ * 2);
    _Float16* W1m_p = (_Float16*)(wsb + 2 * WSZ * 2);
    _Float16* V1t_p = (_Float16*)(wsb + 4 * WSZ * 2);
    _Float16* V1m_p = (_Float16*)(wsb + 6 * WSZ * 2);
    float* W2t = (float*)(wsb + 8 * WSZ * 2);
    _Float16* W2A = (_Float16*)(wsb + 8 * WSZ * 2 + NTRI * H * 4);

    const int k = blockIdx.x;   // W1 row
    const int j = threadIdx.x;  // W1 col
    const int jtA = j >> 4, frA = j & 15, kcA = k >> 5, fgA = (k >> 3) & 3, iiA = k & 7;
    const int idxA = ((jtA * 8 + kcA) * 64 + fgA * 16 + frA) * 8 + iiA;
    const int jtB = k >> 4, frB = k & 15, kcB = j >> 5, fgB = (j >> 3) & 3, iiB = j & 7;
    const int idxB = ((jtB * 8 + kcB) * 64 + fgB * 16 + frB) * 8 + iiB;

    {
        const _Float16 v = (_Float16)mW1[k * H + j];
        W1t_p[idxA] = v;
        W1m_p[idxB] = v;
    }
    {
        const _Float16 v = (_Float16)vW1[k * H + j];
        V1t_p[idxA] = v;
        V1m_p[idxB] = v;
    }
    if (k < NTRI) W2t[k * H + j] = mW2[j * NTRI + k];
    if (k == 0) {
        #pragma unroll
        for (int mm = 0; mm < 16; mm++)
            W2A[j * 16 + mm] = (_Float16)((mm < NTRI) ? mW2[j * NTRI + mm] : 0.f);
    }
}

// ---- k_l0: both layer-0s -> h1m, g1v (fp16) ----
__global__ __launch_bounds__(256) void k_l0(
    const float* __restrict__ x,
    const float* __restrict__ mW0, const float* __restrict__ mb0,
    const float* __restrict__ vW0, const float* __restrict__ vb0,
    _Float16* __restrict__ h1m, _Float16* __restrict__ g1v,
    int E0, int n)
{
    const int j = threadIdx.x;
    const int eb = blockIdx.x * 16;
    float wm[QDIM], wv[QDIM];
    #pragma unroll
    for (int i = 0; i < QDIM; i++) { wm[i] = mW0[i * H + j]; wv[i] = vW0[i * H + j]; }
    const float bm = mb0[j], bv = vb0[j];
    for (int e = 0; e < 16; e++) {
        const int ge = E0 + eb + e;
        float zm = bm, zv = bv;
        if (ge < n) {
            #pragma unroll
            for (int i = 0; i < QDIM; i++) {
                const float q = x[ge * 10 + i];
                zm += q * wm[i];
                zv += q * wv[i];
            }
        }
        h1m[(eb + e) * H + j] = (_Float16)tanhf(zm);
        g1v[(eb + e) * H + j] = (_Float16)tanhf(zv);
    }
}

// ---- k_fwd: D = epi(A @ B), M=32 rows/wave, packed B ----
__global__ __launch_bounds__(256, 4) void k_fwd(
    const _Float16* __restrict__ A,
    const _Float16* __restrict__ Bp,
    const float* __restrict__ bias, const float* __restrict__ w2opt,
    _Float16* __restrict__ Dout)
{
    const int lane = threadIdx.x & 63;
    const int widx = threadIdx.x >> 6;
    const int fr = lane & 15, fg = lane >> 4;
    const int rowbase = (blockIdx.x * 4 + widx) * 32;

    half8 a0[8], a1[8];
    #pragma unroll
    for (int kc = 0; kc < 8; kc++) {
        a0[kc] = *(const half8*)&A[(rowbase + fr) * H + kc * 32 + fg * 8];
        a1[kc] = *(const half8*)&A[(rowbase + 16 + fr) * H + kc * 32 + fg * 8];
    }

    half8 bh[2];
    bh[0] = *(const half8*)&Bp[lane * 8];
    for (int jt = 0; jt < 16; jt++) {
        floatx4 acc0 = (floatx4)(0.f), acc1 = (floatx4)(0.f);
        #pragma unroll
        for (int kc = 0; kc < 8; kc++) {
            const int cur = kc & 1, nxt = cur ^ 1;
            int njt = jt, nkc = kc + 1;
            if (nkc == 8) { njt = jt + 1; nkc = 0; }
            if (njt < 16)
                bh[nxt] = *(const half8*)&Bp[(njt * 8 + nkc) * 512 + lane * 8];
            acc0 = MFMA(a0[kc], bh[cur], acc0);
            acc1 = MFMA(a1[kc], bh[cur], acc1);
        }
        const int j = jt * 16 + fr;
        const float b = bias[j];
        if (w2opt) {
            const float w2 = w2opt[j];
            #pragma unroll
            for (int rr = 0; rr < 4; rr++) {
                const float g0 = tanhf(acc0[rr] + b);
                const float g1 = tanhf(acc1[rr] + b);
                Dout[(rowbase + fg * 4 + rr) * H + j]      = (_Float16)((1.f - g0 * g0) * w2);
                Dout[(rowbase + 16 + fg * 4 + rr) * H + j] = (_Float16)((1.f - g1 * g1) * w2);
            }
        } else {
            #pragma unroll
            for (int rr = 0; rr < 4; rr++) {
                Dout[(rowbase + fg * 4 + rr) * H + j]      = (_Float16)tanhf(acc0[rr] + b);
                Dout[(rowbase + 16 + fg * 4 + rr) * H + j] = (_Float16)tanhf(acc1[rr] + b);
            }
        }
    }
}

// ---- k_ent: ent, entbar, L from h2 ----
__global__ __launch_bounds__(256) void k_ent(
    const _Float16* __restrict__ h2, const float* __restrict__ x,
    const float* __restrict__ W2t, const float* __restrict__ mb2,
    float* __restrict__ entbar, float* __restrict__ Lb,
    int E0, int n)
{
    __shared__ float s_ent[16][NTRI];
    const int tid = threadIdx.x;
    const int eb = blockIdx.x * 16;
    if (tid < 16 * NTRI) {
        const int e = tid / NTRI, m = tid % NTRI;
        float acc = mb2[m];
        const float* wrow = &W2t[m * H];
        for (int j = 0; j < H; j += 8) {
            const half8 hv = *(const half8*)&h2[(eb + e) * H + j];
            const float4 w0 = *(const float4*)&wrow[j];
            const float4 w1 = *(const float4*)&wrow[j + 4];
            acc += (float)hv[0] * w0.x + (float)hv[1] * w0.y
                 + (float)hv[2] * w0.z + (float)hv[3] * w0.w
                 + (float)hv[4] * w1.x + (float)hv[5] * w1.y
                 + (float)hv[6] * w1.z + (float)hv[7] * w1.w;
        }
        s_ent[e][m] = acc;
    }
    __syncthreads();
    if (tid < 16) {
        const int e = tid;
        const int ge = E0 + eb + e;
        const int ti[10] = {0,1,1,2,2,2,3,3,3,3};
        const int tj[10] = {0,0,1,0,1,2,0,1,2,3};
        float L[4][4];
        #pragma unroll
        for (int r = 0; r < 4; r++)
            #pragma unroll
            for (int c = 0; c < 4; c++) L[r][c] = 0.f;
        float sig[10];
        #pragma unroll
        for (int m = 0; m < 10; m++) {
            float v = s_ent[e][m];
            if (ti[m] == tj[m]) {
                sig[m] = 1.f / (1.f + expf(-v));
                L[ti[m]][tj[m]] = softplusf(v);
            } else {
                sig[m] = 1.f;
                L[ti[m]][tj[m]] = v;
            }
        }
        #pragma unroll
        for (int r = 0; r < 4; r++)
            #pragma unroll
            for (int c = 0; c < 4; c++) Lb[(eb + e) * 16 + r * 4 + c] = L[r][c];
        float dq[4];
        #pragma unroll
        for (int r = 0; r < 4; r++) dq[r] = (ge < n) ? x[ge * 10 + 6 + r] : 0.f;
        float a[4];
        #pragma unroll
        for (int c = 0; c < 4; c++) {
            float s = 0.f;
            #pragma unroll
            for (int r = 0; r < 4; r++) s += L[r][c] * dq[r];
            a[c] = s;
        }
        #pragma unroll
        for (int s = 0; s < 4; s++) {
            #pragma unroll
            for (int m = 0; m < 10; m++) {
                float v = ((ti[m] == s) ? a[tj[m]] : 0.f) + dq[ti[m]] * L[s][tj[m]];
                entbar[(eb + e) * 40 + s * 10 + m] = v * sig[m];
            }
        }
    }
}

// ---- k_eh1: s = widx; packed B; 2-way jt ILP; 85-VGPR class (6 waves) ----
__global__ __launch_bounds__(256, 6) void k_eh1(
    const _Float16* __restrict__ h2, const float* __restrict__ entbar,
    const _Float16* __restrict__ W2A,
    const _Float16* __restrict__ Bp,
    const float* __restrict__ mW0, const _Float16* __restrict__ h1m,
    float* __restrict__ Jb)
{
    const int lane = threadIdx.x & 63;
    const int s = threadIdx.x >> 6;
    const int fr = lane & 15, fg = lane >> 4;
    const int ebase = blockIdx.x * 16;
    const int e = ebase + fr;

    float ebv[NTRI];
    #pragma unroll
    for (int m = 0; m < NTRI; m++) ebv[m] = entbar[e * 40 + s * 10 + m];

    // build seed A-fragments in registers (vectorized W2A reads)
    half8 a[8];
    #pragma unroll
    for (int kc = 0; kc < 8; kc++) {
        const half8 hv = *(const half8*)&h2[e * H + kc * 32 + fg * 8];
        half8 sv;
        #pragma unroll
        for (int ii = 0; ii < 8; ii++) {
            const int j = kc * 32 + fg * 8 + ii;
            const half8 wa = *(const half8*)&W2A[j * 16];
            const half8 wb = *(const half8*)&W2A[j * 16 + 8];
            float acc = 0.f;
            #pragma unroll
            for (int m = 0; m < 8; m++) acc += ebv[m] * (float)wa[m];
            acc += ebv[8] * (float)wb[0] + ebv[9] * (float)wb[1];
            const float hh = (float)hv[ii];
            sv[ii] = (_Float16)(acc * (1.f - hh * hh));
        }
        a[kc] = sv;
    }

    float part[4][6];
    #pragma unroll
    for (int rr = 0; rr < 4; rr++)
        #pragma unroll
        for (int i = 0; i < 6; i++) part[rr][i] = 0.f;

    half8 b0[2], b1[2];
    b0[0] = *(const half8*)&Bp[(0 * 8 + 0) * 512 + lane * 8];
    b1[0] = *(const half8*)&Bp[(1 * 8 + 0) * 512 + lane * 8];
    #pragma unroll 1
    for (int p = 0; p < 8; p++) {
        const int jt0 = 2 * p, jt1 = 2 * p + 1;
        floatx4 acc0 = (floatx4)(0.f), acc1 = (floatx4)(0.f);
        #pragma unroll
        for (int kc = 0; kc < 8; kc++) {
            const int cur = kc & 1, nxt = cur ^ 1;
            int pjt0 = jt0, pjt1 = jt1, pkc = kc + 1;
            if (pkc == 8) { pjt0 = jt0 + 2; pjt1 = jt1 + 2; pkc = 0; }
            if (pjt0 < 16) {
                b0[nxt] = *(const half8*)&Bp[(pjt0 * 8 + pkc) * 512 + lane * 8];
                b1[nxt] = *(const half8*)&Bp[(pjt1 * 8 + pkc) * 512 + lane * 8];
            }
            acc0 = MFMA(a[kc], b0[cur], acc0);
            acc1 = MFMA(a[kc], b1[cur], acc1);
        }
        #pragma unroll
        for (int hf = 0; hf < 2; hf++) {
            const int jt = 2 * p + hf;
            const floatx4 acc = hf ? acc1 : acc0;
            const int outk = jt * 16 + fr;
            float w0[6];
            #pragma unroll
            for (int i = 0; i < 6; i++) w0[i] = mW0[i * H + outk];
            #pragma unroll
            for (int rr = 0; rr < 4; rr++) {
                const int er = ebase + fg * 4 + rr;
                const float hh = (float)h1m[er * H + outk];
                const float v = acc[rr] * (1.f - hh * hh);
                #pragma unroll
                for (int i = 0; i < 6; i++) part[rr][i] = fmaf(v, w0[i], part[rr][i]);
            }
        }
    }
    #pragma unroll
    for (int m = 1; m < 16; m <<= 1)
        #pragma unroll
        for (int rr = 0; rr < 4; rr++)
            #pragma unroll
            for (int i = 0; i < 6; i++)
                part[rr][i] += __shfl_xor(part[rr][i], m);
    if (fr == 0) {
        #pragma unroll
        for (int rr = 0; rr < 4; rr++) {
            const int er = ebase + fg * 4 + rr;
            #pragma unroll
            for (int i = 0; i < 6; i++)
                Jb[er * 24 + s * 6 + i] = part[rr][i];
        }
    }
}

// ---- k_gg1: gg2 @ V1m -> t1g -> fused dV (packed B, 2-way jt ILP, 85-VGPR) ----
__global__ __launch_bounds__(256, 6) void k_gg1(
    const _Float16* __restrict__ gg2,
    const _Float16* __restrict__ Bp,
    const float* __restrict__ vW0, const _Float16* __restrict__ g1v,
    float* __restrict__ dVb)
{
    const int lane = threadIdx.x & 63;
    const int widx = threadIdx.x >> 6;
    const int fr = lane & 15, fg = lane >> 4;
    const int rowbase = (blockIdx.x * 4 + widx) * 16;

    half8 a[8];
    #pragma unroll
    for (int kc = 0; kc < 8; kc++)
        a[kc] = *(const half8*)&gg2[(rowbase + fr) * H + kc * 32 + fg * 8];

    float part[4][6];
    #pragma unroll
    for (int rr = 0; rr < 4; rr++)
        #pragma unroll
        for (int i = 0; i < 6; i++) part[rr][i] = 0.f;

    half8 b0[2], b1[2];
    b0[0] = *(const half8*)&Bp[(0 * 8 + 0) * 512 + lane * 8];
    b1[0] = *(const half8*)&Bp[(1 * 8 + 0) * 512 + lane * 8];
    #pragma unroll 1
    for (int p = 0; p < 8; p++) {
        const int jt0 = 2 * p, jt1 = 2 * p + 1;
        floatx4 acc0 = (floatx4)(0.f), acc1 = (floatx4)(0.f);
        #pragma unroll
        for (int kc = 0; kc < 8; kc++) {
            const int cur = kc & 1, nxt = cur ^ 1;
            int pjt0 = jt0, pjt1 = jt1, pkc = kc + 1;
            if (pkc == 8) { pjt0 = jt0 + 2; pjt1 = jt1 + 2; pkc = 0; }
            if (pjt0 < 16) {
                b0[nxt] = *(const half8*)&Bp[(pjt0 * 8 + pkc) * 512 + lane * 8];
                b1[nxt] = *(const half8*)&Bp[(pjt1 * 8 + pkc) * 512 + lane * 8];
            }
            acc0 = MFMA(a[kc], b0[cur], acc0);
            acc1 = MFMA(a[kc], b1[cur], acc1);
        }
        #pragma unroll
        for (int hf = 0; hf < 2; hf++) {
            const int jt = 2 * p + hf;
            const floatx4 acc = hf ? acc1 : acc0;
            const int outk = jt * 16 + fr;
            float w0[6];
            #pragma unroll
            for (int i = 0; i < 6; i++) w0[i] = vW0[i * H + outk];
            #pragma unroll
            for (int rr = 0; rr < 4; rr++) {
                const int er = rowbase + fg * 4 + rr;
                const float g = (float)g1v[er * H + outk];
                const float v = acc[rr] * (1.f - g * g);
                #pragma unroll
                for (int i = 0; i < 6; i++) part[rr][i] = fmaf(v, w0[i], part[rr][i]);
            }
        }
    }
    #pragma unroll
    for (int m = 1; m < 16; m <<= 1)
        #pragma unroll
        for (int rr = 0; rr < 4; rr++)
            #pragma unroll
            for (int i = 0; i < 6; i++)
                part[rr][i] += __shfl_xor(part[rr][i], m);
    if (fr == 0) {
        #pragma unroll
        for (int rr = 0; rr < 4; rr++) {
            const int er = rowbase + fg * 4 + rr;
            #pragma unroll
            for (int i = 0; i < 6; i++)
                dVb[er * 6 + i] = part[rr][i];
        }
    }
}

// ---- k_fin: per-element finalize ----
__global__ __launch_bounds__(256) void k_fin(
    const float* __restrict__ x,
    const float* __restrict__ Lb, const float* __restrict__ Jb,
    const float* __restrict__ dVb,
    float* __restrict__ out, int E0, int n)
{
    const int e = blockIdx.x * 256 + threadIdx.x;
    const int ge = E0 + e;
    if (ge >= n) return;
    float q[6], dq[4];
    #pragma unroll
    for (int i = 0; i < 6; i++) q[i] = x[ge * 10 + i];
    #pragma unroll
    for (int r = 0; r < 4; r++) dq[r] = x[ge * 10 + 6 + r];
    const float x1a = q[2], x1b = q[3], x2a = q[4], x2b = q[5];
    float J[4][6];
    #pragma unroll
    for (int r = 0; r < 4; r++)
        #pragma unroll
        for (int i = 0; i < 6; i++) J[r][i] = Jb[e * 24 + r * 6 + i];
    float dV[6];
    #pragma unroll
    for (int i = 0; i < 6; i++) dV[i] = dVb[e * 6 + i];
    float Lm[16];
    #pragma unroll
    for (int i = 0; i < 16; i++) Lm[i] = Lb[e * 16 + i];

    float G[4][4];
    #pragma unroll
    for (int r = 0; r < 4; r++) {
        G[r][0] = J[r][0];
        G[r][1] = J[r][1];
        G[r][2] = -x2a * J[r][2] + x1a * J[r][4];
        G[r][3] = -x2b * J[r][3] + x1b * J[r][5];
    }
    float gL[6];
    #pragma unroll
    for (int i = 0; i < 6; i++) {
        float s = 0.f;
        #pragma unroll
        for (int r = 0; r < 4; r++) s += dq[r] * J[r][i];
        gL[i] = 0.5f * s - dV[i];
    }
    float dLdq[4];
    dLdq[0] = gL[0];
    dLdq[1] = gL[1];
    dLdq[2] = -x2a * gL[2] + x1a * gL[4];
    dLdq[3] = -x2b * gL[3] + x1b * gL[5];
    float b[4];
    #pragma unroll
    for (int r = 0; r < 4; r++) {
        float s = 0.f;
        #pragma unroll
        for (int c = 0; c < 4; c++) s += G[r][c] * dq[c];
        b[r] = dLdq[r] - s;
    }
    float M[4][4];
    #pragma unroll
    for (int r = 0; r < 4; r++)
        #pragma unroll
        for (int c = 0; c <= r; c++) {
            float s = 0.f;
            #pragma unroll
            for (int k = 0; k < 4; k++) s += Lm[r * 4 + k] * Lm[c * 4 + k];
            M[r][c] = s;
        }
    #pragma unroll
    for (int r = 0; r < 4; r++) M[r][r] += EPS;
    float C00 = sqrtf(M[0][0]);
    float C10 = M[1][0] / C00, C20 = M[2][0] / C00, C30 = M[3][0] / C00;
    float C11 = sqrtf(M[1][1] - C10 * C10);
    float C21 = (M[2][1] - C20 * C10) / C11;
    float C31 = (M[3][1] - C30 * C10) / C11;
    float C22 = sqrtf(M[2][2] - C20 * C20 - C21 * C21);
    float C32 = (M[3][2] - C30 * C20 - C31 * C21) / C22;
    float C33 = sqrtf(M[3][3] - C30 * C30 - C31 * C31 - C32 * C32);
    float y0 = b[0] / C00;
    float y1 = (b[1] - C10 * y0) / C11;
    float y2 = (b[2] - C20 * y0 - C21 * y1) / C22;
    float y3 = (b[3] - C30 * y0 - C31 * y1 - C32 * y2) / C33;
    float d3 = y3 / C33;
    float d2 = (y2 - C32 * d3) / C22;
    float d1 = (y1 - C21 * d2 - C31 * d3) / C11;
    float d0 = (y0 - C10 * d1 - C20 * d2 - C30 * d3) / C00;

    float* o = &out[ge * 10];
    o[0] = dq[0];
    o[1] = dq[1];
    o[2] = -x2a * dq[2];
    o[3] = -x2b * dq[3];
    o[4] = x1a * dq[2];
    o[5] = x1b * dq[3];
    o[6] = d0; o[7] = d1; o[8] = d2; o[9] = d3;
}

extern "C" void kernel_launch(void* const* d_in, const int* in_sizes, int n_in,
                              void* d_out, int out_size, void* d_ws, size_t ws_size,
                              hipStream_t stream) {
    const float* x   = (const float*)d_in[0];
    const float* mW0 = (const float*)d_in[1];
    const float* mb0 = (const float*)d_in[2];
    const float* mW1 = (const float*)d_in[3];
    const float* mb1 = (const float*)d_in[4];
    const float* mW2 = (const float*)d_in[5];
    const float* mb2 = (const float*)d_in[6];
    const float* vW0 = (const float*)d_in[7];
    const float* vb0 = (const float*)d_in[8];
    const float* vW1 = (const float*)d_in[9];
    const float* vb1 = (const float*)d_in[10];
    const float* vW2 = (const float*)d_in[11];
    float* out = (float*)d_out;
    const int n = in_sizes[0] / 10;

    char* wsb = (char*)d_ws;
    _Float16* W1t_p = (_Float16*)(wsb + 0 * WSZ * 2);
    _Float16* W1m_p = (_Float16*)(wsb + 2 * WSZ * 2);
    _Float16* V1t_p = (_Float16*)(wsb + 4 * WSZ * 2);
    _Float16* V1m_p = (_Float16*)(wsb + 6 * WSZ * 2);
    float*    W2t = (float*)(wsb + 8 * WSZ * 2);
    _Float16* W2A = (_Float16*)(wsb + 8 * WSZ * 2 + NTRI * H * 4);
    const size_t wend = 8 * WSZ * 2 + NTRI * H * 4 + H * 16 * 2;

    size_t C = 65536;
    while (C > 256 && wend + 2392ull * C > ws_size) C >>= 1;
    if ((size_t)n < C) C = (size_t)n;

    prep_kernel<<<H, H, 0, stream>>>(mW1, vW1, mW2, d_ws);

    char* cb = wsb + wend;
    _Float16* h1m  = (_Float16*)(cb);
    _Float16* g1v  = (_Float16*)(cb + 512 * C);
    _Float16* h2   = (_Float16*)(cb + 1024 * C);
    _Float16* gg2  = (_Float16*)(cb + 1536 * C);
    float* entbar  = (float*)(cb + 2048 * C);
    float* Lb      = (float*)(cb + 2208 * C);
    float* Jb      = (float*)(cb + 2272 * C);
    float* dVb     = (float*)(cb + 2368 * C);

    const int Ci = (int)C;
    for (int E0 = 0; E0 < n; E0 += Ci) {
        k_l0<<<Ci / 16, 256, 0, stream>>>(x, mW0, mb0, vW0, vb0, h1m, g1v, E0, n);
        k_fwd<<<Ci / 128, 256, 0, stream>>>(h1m, W1t_p, mb1, nullptr, h2);
        k_fwd<<<Ci / 128, 256, 0, stream>>>(g1v, V1t_p, vb1, vW2, gg2);
        k_ent<<<Ci / 16, 256, 0, stream>>>(h2, x, W2t, mb2, entbar, Lb, E0, n);
        k_eh1<<<Ci / 16, 256, 0, stream>>>(h2, entbar, W2A, W1m_p, mW0, h1m, Jb);
        k_gg1<<<Ci / 64, 256, 0, stream>>>(gg2, V1m_p, vW0, g1v, dVb);
        k_fin<<<Ci / 256, 256, 0, stream>>>(x, Lb, Jb, dVb, out, E0, n);
    }
}

// Round 27
// 369.227 us; speedup vs baseline: 1.3802x; 1.3802x over previous
//
#include <hip/hip_runtime.h>
#include <math.h>

#define EPS 1e-3f
#define H 256
#define QDIM 6
#define NTRI 10

typedef _Float16 half8 __attribute__((ext_vector_type(8)));
typedef float floatx4 __attribute__((ext_vector_type(4)));

#define WSZ (H * H)
#define MFMA(A, B, C) __builtin_amdgcn_mfma_f32_16x16x32_f16((A), (B), (C), 0, 0, 0)

__device__ __forceinline__ float softplusf(float x) {
    if (x > 20.f) return x;
    return log1pf(expf(x));
}

// ---- prep: fragment-packed fp16 B matrices; W2t fp32; W2A fp16 ----
__global__ __launch_bounds__(256) void prep_kernel(
    const float* __restrict__ mW1, const float* __restrict__ vW1,
    const float* __restrict__ mW2, void* __restrict__ ws)
{
    char* wsb = (char*)ws;
    _Float16* W1t_p = (_Float16*)(wsb + 0 * WSZ * 2);
    _Float16* W1m_p = (_Float16*)(wsb + 2 * WSZ * 2);
    _Float16* V1t_p = (_Float16*)(wsb + 4 * WSZ * 2);
    _Float16* V1m_p = (_Float16*)(wsb + 6 * WSZ * 2);
    float* W2t = (float*)(wsb + 8 * WSZ * 2);
    _Float16* W2A = (_Float16*)(wsb + 8 * WSZ * 2 + NTRI * H * 4);

    const int k = blockIdx.x;   // W1 row
    const int j = threadIdx.x;  // W1 col
    const int jtA = j >> 4, frA = j & 15, kcA = k >> 5, fgA = (k >> 3) & 3, iiA = k & 7;
    const int idxA = ((jtA * 8 + kcA) * 64 + fgA * 16 + frA) * 8 + iiA;
    const int jtB = k >> 4, frB = k & 15, kcB = j >> 5, fgB = (j >> 3) & 3, iiB = j & 7;
    const int idxB = ((jtB * 8 + kcB) * 64 + fgB * 16 + frB) * 8 + iiB;

    {
        const _Float16 v = (_Float16)mW1[k * H + j];
        W1t_p[idxA] = v;
        W1m_p[idxB] = v;
    }
    {
        const _Float16 v = (_Float16)vW1[k * H + j];
        V1t_p[idxA] = v;
        V1m_p[idxB] = v;
    }
    if (k < NTRI) W2t[k * H + j] = mW2[j * NTRI + k];
    if (k == 0) {
        #pragma unroll
        for (int mm = 0; mm < 16; mm++)
            W2A[j * 16 + mm] = (_Float16)((mm < NTRI) ? mW2[j * NTRI + mm] : 0.f);
    }
}

// ---- k_l0: both layer-0s -> h1m, g1v (fp16) ----
__global__ __launch_bounds__(256) void k_l0(
    const float* __restrict__ x,
    const float* __restrict__ mW0, const float* __restrict__ mb0,
    const float* __restrict__ vW0, const float* __restrict__ vb0,
    _Float16* __restrict__ h1m, _Float16* __restrict__ g1v,
    int E0, int n)
{
    const int j = threadIdx.x;
    const int eb = blockIdx.x * 16;
    float wm[QDIM], wv[QDIM];
    #pragma unroll
    for (int i = 0; i < QDIM; i++) { wm[i] = mW0[i * H + j]; wv[i] = vW0[i * H + j]; }
    const float bm = mb0[j], bv = vb0[j];
    for (int e = 0; e < 16; e++) {
        const int ge = E0 + eb + e;
        float zm = bm, zv = bv;
        if (ge < n) {
            #pragma unroll
            for (int i = 0; i < QDIM; i++) {
                const float q = x[ge * 10 + i];
                zm += q * wm[i];
                zv += q * wv[i];
            }
        }
        h1m[(eb + e) * H + j] = (_Float16)tanhf(zm);
        g1v[(eb + e) * H + j] = (_Float16)tanhf(zv);
    }
}

// ---- k_fwd: D = epi(A @ B), M=32 rows/wave, packed B ----
__global__ __launch_bounds__(256, 4) void k_fwd(
    const _Float16* __restrict__ A,
    const _Float16* __restrict__ Bp,
    const float* __restrict__ bias, const float* __restrict__ w2opt,
    _Float16* __restrict__ Dout)
{
    const int lane = threadIdx.x & 63;
    const int widx = threadIdx.x >> 6;
    const int fr = lane & 15, fg = lane >> 4;
    const int rowbase = (blockIdx.x * 4 + widx) * 32;

    half8 a0[8], a1[8];
    #pragma unroll
    for (int kc = 0; kc < 8; kc++) {
        a0[kc] = *(const half8*)&A[(rowbase + fr) * H + kc * 32 + fg * 8];
        a1[kc] = *(const half8*)&A[(rowbase + 16 + fr) * H + kc * 32 + fg * 8];
    }

    half8 bh[2];
    bh[0] = *(const half8*)&Bp[lane * 8];
    for (int jt = 0; jt < 16; jt++) {
        floatx4 acc0 = (floatx4)(0.f), acc1 = (floatx4)(0.f);
        #pragma unroll
        for (int kc = 0; kc < 8; kc++) {
            const int cur = kc & 1, nxt = cur ^ 1;
            int njt = jt, nkc = kc + 1;
            if (nkc == 8) { njt = jt + 1; nkc = 0; }
            if (njt < 16)
                bh[nxt] = *(const half8*)&Bp[(njt * 8 + nkc) * 512 + lane * 8];
            acc0 = MFMA(a0[kc], bh[cur], acc0);
            acc1 = MFMA(a1[kc], bh[cur], acc1);
        }
        const int j = jt * 16 + fr;
        const float b = bias[j];
        if (w2opt) {
            const float w2 = w2opt[j];
            #pragma unroll
            for (int rr = 0; rr < 4; rr++) {
                const float g0 = tanhf(acc0[rr] + b);
                const float g1 = tanhf(acc1[rr] + b);
                Dout[(rowbase + fg * 4 + rr) * H + j]      = (_Float16)((1.f - g0 * g0) * w2);
                Dout[(rowbase + 16 + fg * 4 + rr) * H + j] = (_Float16)((1.f - g1 * g1) * w2);
            }
        } else {
            #pragma unroll
            for (int rr = 0; rr < 4; rr++) {
                Dout[(rowbase + fg * 4 + rr) * H + j]      = (_Float16)tanhf(acc0[rr] + b);
                Dout[(rowbase + 16 + fg * 4 + rr) * H + j] = (_Float16)tanhf(acc1[rr] + b);
            }
        }
    }
}

// ---- k_ent: ent, entbar, L from h2 ----
__global__ __launch_bounds__(256) void k_ent(
    const _Float16* __restrict__ h2, const float* __restrict__ x,
    const float* __restrict__ W2t, const float* __restrict__ mb2,
    float* __restrict__ entbar, float* __restrict__ Lb,
    int E0, int n)
{
    __shared__ float s_ent[16][NTRI];
    const int tid = threadIdx.x;
    const int eb = blockIdx.x * 16;
    if (tid < 16 * NTRI) {
        const int e = tid / NTRI, m = tid % NTRI;
        float acc = mb2[m];
        const float* wrow = &W2t[m * H];
        for (int j = 0; j < H; j += 8) {
            const half8 hv = *(const half8*)&h2[(eb + e) * H + j];
            const float4 w0 = *(const float4*)&wrow[j];
            const float4 w1 = *(const float4*)&wrow[j + 4];
            acc += (float)hv[0] * w0.x + (float)hv[1] * w0.y
                 + (float)hv[2] * w0.z + (float)hv[3] * w0.w
                 + (float)hv[4] * w1.x + (float)hv[5] * w1.y
                 + (float)hv[6] * w1.z + (float)hv[7] * w1.w;
        }
        s_ent[e][m] = acc;
    }
    __syncthreads();
    if (tid < 16) {
        const int e = tid;
        const int ge = E0 + eb + e;
        const int ti[10] = {0,1,1,2,2,2,3,3,3,3};
        const int tj[10] = {0,0,1,0,1,2,0,1,2,3};
        float L[4][4];
        #pragma unroll
        for (int r = 0; r < 4; r++)
            #pragma unroll
            for (int c = 0; c < 4; c++) L[r][c] = 0.f;
        float sig[10];
        #pragma unroll
        for (int m = 0; m < 10; m++) {
            float v = s_ent[e][m];
            if (ti[m] == tj[m]) {
                sig[m] = 1.f / (1.f + expf(-v));
                L[ti[m]][tj[m]] = softplusf(v);
            } else {
                sig[m] = 1.f;
                L[ti[m]][tj[m]] = v;
            }
        }
        #pragma unroll
        for (int r = 0; r < 4; r++)
            #pragma unroll
            for (int c = 0; c < 4; c++) Lb[(eb + e) * 16 + r * 4 + c] = L[r][c];
        float dq[4];
        #pragma unroll
        for (int r = 0; r < 4; r++) dq[r] = (ge < n) ? x[ge * 10 + 6 + r] : 0.f;
        float a[4];
        #pragma unroll
        for (int c = 0; c < 4; c++) {
            float s = 0.f;
            #pragma unroll
            for (int r = 0; r < 4; r++) s += L[r][c] * dq[r];
            a[c] = s;
        }
        #pragma unroll
        for (int s = 0; s < 4; s++) {
            #pragma unroll
            for (int m = 0; m < 10; m++) {
                float v = ((ti[m] == s) ? a[tj[m]] : 0.f) + dq[ti[m]] * L[s][tj[m]];
                entbar[(eb + e) * 40 + s * 10 + m] = v * sig[m];
            }
        }
    }
}

// ---- k_eh1: s = widx; packed B; vectorized W2A; cap(256,4) — best measured ----
__global__ __launch_bounds__(256, 4) void k_eh1(
    const _Float16* __restrict__ h2, const float* __restrict__ entbar,
    const _Float16* __restrict__ W2A,
    const _Float16* __restrict__ Bp,
    const float* __restrict__ mW0, const _Float16* __restrict__ h1m,
    float* __restrict__ Jb)
{
    const int lane = threadIdx.x & 63;
    const int s = threadIdx.x >> 6;
    const int fr = lane & 15, fg = lane >> 4;
    const int ebase = blockIdx.x * 16;
    const int e = ebase + fr;

    float ebv[NTRI];
    #pragma unroll
    for (int m = 0; m < NTRI; m++) ebv[m] = entbar[e * 40 + s * 10 + m];

    // build seed A-fragments in registers (vectorized W2A reads)
    half8 a[8];
    #pragma unroll
    for (int kc = 0; kc < 8; kc++) {
        const half8 hv = *(const half8*)&h2[e * H + kc * 32 + fg * 8];
        half8 sv;
        #pragma unroll
        for (int ii = 0; ii < 8; ii++) {
            const int j = kc * 32 + fg * 8 + ii;
            const half8 wa = *(const half8*)&W2A[j * 16];
            const half8 wb = *(const half8*)&W2A[j * 16 + 8];
            float acc = 0.f;
            #pragma unroll
            for (int m = 0; m < 8; m++) acc += ebv[m] * (float)wa[m];
            acc += ebv[8] * (float)wb[0] + ebv[9] * (float)wb[1];
            const float hh = (float)hv[ii];
            sv[ii] = (_Float16)(acc * (1.f - hh * hh));
        }
        a[kc] = sv;
    }

    float part[4][6];
    #pragma unroll
    for (int rr = 0; rr < 4; rr++)
        #pragma unroll
        for (int i = 0; i < 6; i++) part[rr][i] = 0.f;

    half8 bh[2];
    bh[0] = *(const half8*)&Bp[lane * 8];
    for (int jt = 0; jt < 16; jt++) {
        floatx4 acc = (floatx4)(0.f);
        #pragma unroll
        for (int kc = 0; kc < 8; kc++) {
            const int cur = kc & 1, nxt = cur ^ 1;
            int njt = jt, nkc = kc + 1;
            if (nkc == 8) { njt = jt + 1; nkc = 0; }
            if (njt < 16)
                bh[nxt] = *(const half8*)&Bp[(njt * 8 + nkc) * 512 + lane * 8];
            acc = MFMA(a[kc], bh[cur], acc);
        }
        const int outk = jt * 16 + fr;
        float w0[6];
        #pragma unroll
        for (int i = 0; i < 6; i++) w0[i] = mW0[i * H + outk];
        #pragma unroll
        for (int rr = 0; rr < 4; rr++) {
            const int er = ebase + fg * 4 + rr;
            const float hh = (float)h1m[er * H + outk];
            const float v = acc[rr] * (1.f - hh * hh);
            #pragma unroll
            for (int i = 0; i < 6; i++) part[rr][i] = fmaf(v, w0[i], part[rr][i]);
        }
    }
    #pragma unroll
    for (int m = 1; m < 16; m <<= 1)
        #pragma unroll
        for (int rr = 0; rr < 4; rr++)
            #pragma unroll
            for (int i = 0; i < 6; i++)
                part[rr][i] += __shfl_xor(part[rr][i], m);
    if (fr == 0) {
        #pragma unroll
        for (int rr = 0; rr < 4; rr++) {
            const int er = ebase + fg * 4 + rr;
            #pragma unroll
            for (int i = 0; i < 6; i++)
                Jb[er * 24 + s * 6 + i] = part[rr][i];
        }
    }
}

// ---- k_gg1: gg2 @ V1m -> t1g -> fused dV (packed B, 2-way jt ILP, cap 4) ----
__global__ __launch_bounds__(256, 4) void k_gg1(
    const _Float16* __restrict__ gg2,
    const _Float16* __restrict__ Bp,
    const float* __restrict__ vW0, const _Float16* __restrict__ g1v,
    float* __restrict__ dVb)
{
    const int lane = threadIdx.x & 63;
    const int widx = threadIdx.x >> 6;
    const int fr = lane & 15, fg = lane >> 4;
    const int rowbase = (blockIdx.x * 4 + widx) * 16;

    half8 a[8];
    #pragma unroll
    for (int kc = 0; kc < 8; kc++)
        a[kc] = *(const half8*)&gg2[(rowbase + fr) * H + kc * 32 + fg * 8];

    float part[4][6];
    #pragma unroll
    for (int rr = 0; rr < 4; rr++)
        #pragma unroll
        for (int i = 0; i < 6; i++) part[rr][i] = 0.f;

    half8 b0[2], b1[2];
    b0[0] = *(const half8*)&Bp[(0 * 8 + 0) * 512 + lane * 8];
    b1[0] = *(const half8*)&Bp[(1 * 8 + 0) * 512 + lane * 8];
    #pragma unroll 1
    for (int p = 0; p < 8; p++) {
        const int jt0 = 2 * p, jt1 = 2 * p + 1;
        floatx4 acc0 = (floatx4)(0.f), acc1 = (floatx4)(0.f);
        #pragma unroll
        for (int kc = 0; kc < 8; kc++) {
            const int cur = kc & 1, nxt = cur ^ 1;
            int pjt0 = jt0, pjt1 = jt1, pkc = kc + 1;
            if (pkc == 8) { pjt0 = jt0 + 2; pjt1 = jt1 + 2; pkc = 0; }
            if (pjt0 < 16) {
                b0[nxt] = *(const half8*)&Bp[(pjt0 * 8 + pkc) * 512 + lane * 8];
                b1[nxt] = *(const half8*)&Bp[(pjt1 * 8 + pkc) * 512 + lane * 8];
            }
            acc0 = MFMA(a[kc], b0[cur], acc0);
            acc1 = MFMA(a[kc], b1[cur], acc1);
        }
        #pragma unroll
        for (int hf = 0; hf < 2; hf++) {
            const int jt = 2 * p + hf;
            const floatx4 acc = hf ? acc1 : acc0;
            const int outk = jt * 16 + fr;
            float w0[6];
            #pragma unroll
            for (int i = 0; i < 6; i++) w0[i] = vW0[i * H + outk];
            #pragma unroll
            for (int rr = 0; rr < 4; rr++) {
                const int er = rowbase + fg * 4 + rr;
                const float g = (float)g1v[er * H + outk];
                const float v = acc[rr] * (1.f - g * g);
                #pragma unroll
                for (int i = 0; i < 6; i++) part[rr][i] = fmaf(v, w0[i], part[rr][i]);
            }
        }
    }
    #pragma unroll
    for (int m = 1; m < 16; m <<= 1)
        #pragma unroll
        for (int rr = 0; rr < 4; rr++)
            #pragma unroll
            for (int i = 0; i < 6; i++)
                part[rr][i] += __shfl_xor(part[rr][i], m);
    if (fr == 0) {
        #pragma unroll
        for (int rr = 0; rr < 4; rr++) {
            const int er = rowbase + fg * 4 + rr;
            #pragma unroll
            for (int i = 0; i < 6; i++)
                dVb[er * 6 + i] = part[rr][i];
        }
    }
}

// ---- k_fin: per-element finalize ----
__global__ __launch_bounds__(256) void k_fin(
    const float* __restrict__ x,
    const float* __restrict__ Lb, const float* __restrict__ Jb,
    const float* __restrict__ dVb,
    float* __restrict__ out, int E0, int n)
{
    const int e = blockIdx.x * 256 + threadIdx.x;
    const int ge = E0 + e;
    if (ge >= n) return;
    float q[6], dq[4];
    #pragma unroll
    for (int i = 0; i < 6; i++) q[i] = x[ge * 10 + i];
    #pragma unroll
    for (int r = 0; r < 4; r++) dq[r] = x[ge * 10 + 6 + r];
    const float x1a = q[2], x1b = q[3], x2a = q[4], x2b = q[5];
    float J[4][6];
    #pragma unroll
    for (int r = 0; r < 4; r++)
        #pragma unroll
        for (int i = 0; i < 6; i++) J[r][i] = Jb[e * 24 + r * 6 + i];
    float dV[6];
    #pragma unroll
    for (int i = 0; i < 6; i++) dV[i] = dVb[e * 6 + i];
    float Lm[16];
    #pragma unroll
    for (int i = 0; i < 16; i++) Lm[i] = Lb[e * 16 + i];

    float G[4][4];
    #pragma unroll
    for (int r = 0; r < 4; r++) {
        G[r][0] = J[r][0];
        G[r][1] = J[r][1];
        G[r][2] = -x2a * J[r][2] + x1a * J[r][4];
        G[r][3] = -x2b * J[r][3] + x1b * J[r][5];
    }
    float gL[6];
    #pragma unroll
    for (int i = 0; i < 6; i++) {
        float s = 0.f;
        #pragma unroll
        for (int r = 0; r < 4; r++) s += dq[r] * J[r][i];
        gL[i] = 0.5f * s - dV[i];
    }
    float dLdq[4];
    dLdq[0] = gL[0];
    dLdq[1] = gL[1];
    dLdq[2] = -x2a * gL[2] + x1a * gL[4];
    dLdq[3] = -x2b * gL[3] + x1b * gL[5];
    float b[4];
    #pragma unroll
    for (int r = 0; r < 4; r++) {
        float s = 0.f;
        #pragma unroll
        for (int c = 0; c < 4; c++) s += G[r][c] * dq[c];
        b[r] = dLdq[r] - s;
    }
    float M[4][4];
    #pragma unroll
    for (int r = 0; r < 4; r++)
        #pragma unroll
        for (int c = 0; c <= r; c++) {
            float s = 0.f;
            #pragma unroll
            for (int k = 0; k < 4; k++) s += Lm[r * 4 + k] * Lm[c * 4 + k];
            M[r][c] = s;
        }
    #pragma unroll
    for (int r = 0; r < 4; r++) M[r][r] += EPS;
    float C00 = sqrtf(M[0][0]);
    float C10 = M[1][0] / C00, C20 = M[2][0] / C00, C30 = M[3][0] / C00;
    float C11 = sqrtf(M[1][1] - C10 * C10);
    float C21 = (M[2][1] - C20 * C10) / C11;
    float C31 = (M[3][1] - C30 * C10) / C11;
    float C22 = sqrtf(M[2][2] - C20 * C20 - C21 * C21);
    float C32 = (M[3][2] - C30 * C20 - C31 * C21) / C22;
    float C33 = sqrtf(M[3][3] - C30 * C30 - C31 * C31 - C32 * C32);
    float y0 = b[0] / C00;
    float y1 = (b[1] - C10 * y0) / C11;
    float y2 = (b[2] - C20 * y0 - C21 * y1) / C22;
    float y3 = (b[3] - C30 * y0 - C31 * y1 - C32 * y2) / C33;
    float d3 = y3 / C33;
    float d2 = (y2 - C32 * d3) / C22;
    float d1 = (y1 - C21 * d2 - C31 * d3) / C11;
    float d0 = (y0 - C10 * d1 - C20 * d2 - C30 * d3) / C00;

    float* o = &out[ge * 10];
    o[0] = dq[0];
    o[1] = dq[1];
    o[2] = -x2a * dq[2];
    o[3] = -x2b * dq[3];
    o[4] = x1a * dq[2];
    o[5] = x1b * dq[3];
    o[6] = d0; o[7] = d1; o[8] = d2; o[9] = d3;
}

extern "C" void kernel_launch(void* const* d_in, const int* in_sizes, int n_in,
                              void* d_out, int out_size, void* d_ws, size_t ws_size,
                              hipStream_t stream) {
    const float* x   = (const float*)d_in[0];
    const float* mW0 = (const float*)d_in[1];
    const float* mb0 = (const float*)d_in[2];
    const float* mW1 = (const float*)d_in[3];
    const float* mb1 = (const float*)d_in[4];
    const float* mW2 = (const float*)d_in[5];
    const float* mb2 = (const float*)d_in[6];
    const float* vW0 = (const float*)d_in[7];
    const float* vb0 = (const float*)d_in[8];
    const float* vW1 = (const float*)d_in[9];
    const float* vb1 = (const float*)d_in[10];
    const float* vW2 = (const float*)d_in[11];
    float* out = (float*)d_out;
    const int n = in_sizes[0] / 10;

    char* wsb = (char*)d_ws;
    _Float16* W1t_p = (_Float16*)(wsb + 0 * WSZ * 2);
    _Float16* W1m_p = (_Float16*)(wsb + 2 * WSZ * 2);
    _Float16* V1t_p = (_Float16*)(wsb + 4 * WSZ * 2);
    _Float16* V1m_p = (_Float16*)(wsb + 6 * WSZ * 2);
    float*    W2t = (float*)(wsb + 8 * WSZ * 2);
    _Float16* W2A = (_Float16*)(wsb + 8 * WSZ * 2 + NTRI * H * 4);
    const size_t wend = 8 * WSZ * 2 + NTRI * H * 4 + H * 16 * 2;

    size_t C = 65536;
    while (C > 256 && wend + 2392ull * C > ws_size) C >>= 1;
    if ((size_t)n < C) C = (size_t)n;

    prep_kernel<<<H, H, 0, stream>>>(mW1, vW1, mW2, d_ws);

    char* cb = wsb + wend;
    _Float16* h1m  = (_Float16*)(cb);
    _Float16* g1v  = (_Float16*)(cb + 512 * C);
    _Float16* h2   = (_Float16*)(cb + 1024 * C);
    _Float16* gg2  = (_Float16*)(cb + 1536 * C);
    float* entbar  = (float*)(cb + 2048 * C);
    float* Lb      = (float*)(cb + 2208 * C);
    float* Jb      = (float*)(cb + 2272 * C);
    float* dVb     = (float*)(cb + 2368 * C);

    const int Ci = (int)C;
    for (int E0 = 0; E0 < n; E0 += Ci) {
        k_l0<<<Ci / 16, 256, 0, stream>>>(x, mW0, mb0, vW0, vb0, h1m, g1v, E0, n);
        k_fwd<<<Ci / 128, 256, 0, stream>>>(h1m, W1t_p, mb1, nullptr, h2);
        k_fwd<<<Ci / 128, 256, 0, stream>>>(g1v, V1t_p, vb1, vW2, gg2);
        k_ent<<<Ci / 16, 256, 0, stream>>>(h2, x, W2t, mb2, entbar, Lb, E0, n);
        k_eh1<<<Ci / 16, 256, 0, stream>>>(h2, entbar, W2A, W1m_p, mW0, h1m, Jb);
        k_gg1<<<Ci / 64, 256, 0, stream>>>(gg2, V1m_p, vW0, g1v, dVb);
        k_fin<<<Ci / 256, 256, 0, stream>>>(x, Lb, Jb, dVb, out, E0, n);
    }
}